// Round 1
// baseline (27.749 us; speedup 1.0000x reference)
//
#include <hip/hip_runtime.h>

#define V 10
#define L 45            // V*(V-1)/2
#define NCOEF 14
#define NSAMP 65536

// col index j for pair l (tril_indices(V, k=-1) row-major order)
__constant__ int c_col[L] = {
    0,
    0,1,
    0,1,2,
    0,1,2,3,
    0,1,2,3,4,
    0,1,2,3,4,5,
    0,1,2,3,4,5,6,
    0,1,2,3,4,5,6,7,
    0,1,2,3,4,5,6,7,8
};

__global__ __launch_bounds__(256) void decor_main(
    const float* __restrict__ x, const float* __restrict__ log_d,
    const float* __restrict__ params,
    float* __restrict__ out, float* __restrict__ Mout, float* __restrict__ logd_out)
{
    constexpr int BS = 64;  // samples per block
    __shared__ float xs[BS][V];
    __shared__ float lam[BS][L + 3];   // pad to 48 to spread LDS banks

    const int tid = threadIdx.x;
    const int n0  = blockIdx.x * BS;

    // ---- load x tile, coalesced (640 floats) ----
    for (int idx = tid; idx < BS * V; idx += 256) {
        xs[idx / V][idx % V] = x[(size_t)n0 * V + idx];
    }
    __syncthreads();

    // ---- compute lambdas: BS*L = 2880 evals ----
    // knots: uniform, spacing d = 10/11, t0 = -5 - 3d; u = (x+5)/d + 3
    const float inv_d = 11.0f / 10.0f;
    const float c16 = 1.0f / 6.0f;
    for (int idx = tid; idx < BS * L; idx += 256) {
        int nl = idx / L;
        int l  = idx - nl * L;
        float xv = xs[nl][c_col[l]];
        xv = fminf(fmaxf(xv, -5.0f), 5.0f);
        float u  = (xv + 5.0f) * inv_d + 3.0f;
        int   i  = (int)floorf(u);
        i = max(3, min(i, 14));           // reference indicator puts x=5 in [t14,t15)
        float f  = u - (float)i;
        float omf = 1.0f - f;
        float f2 = f * f, f3 = f2 * f;
        float N0 = omf * omf * omf * c16;
        float N1 = (3.0f * f3 - 6.0f * f2 + 4.0f) * c16;
        float N2 = (-3.0f * f3 + 3.0f * f2 + 3.0f * f + 1.0f) * c16;
        float N3 = f3 * c16;              // == 0 when i==14 (f==0)
        int k0 = i - 3;
        int k3 = min(k0 + 3, NCOEF - 1);  // B_14 dropped by reference; N3==0 there
        float lv = N0 * params[(k0    ) * L + l]
                 + N1 * params[(k0 + 1) * L + l]
                 + N2 * params[(k0 + 2) * L + l]
                 + N3 * params[(k3    ) * L + l];
        lam[nl][l] = lv;
    }
    __syncthreads();

    // ---- write M: BS*100 floats, coalesced ----
    for (int idx = tid; idx < BS * V * V; idx += 256) {
        int nl = idx / (V * V);
        int ij = idx - nl * V * V;
        int i = ij / V, j = ij - i * V;
        float v;
        if (i == j)      v = 1.0f;
        else if (j < i)  v = lam[nl][i * (i - 1) / 2 + j];
        else             v = 0.0f;
        Mout[(size_t)n0 * V * V + idx] = v;
    }

    // ---- out = M @ x  and log_d passthrough: BS*V floats each ----
    for (int idx = tid; idx < BS * V; idx += 256) {
        int nl = idx / V;
        int i  = idx - nl * V;
        float acc = xs[nl][i];
        for (int j = 0; j < i; ++j)
            acc += lam[nl][i * (i - 1) / 2 + j] * xs[nl][j];
        out[(size_t)n0 * V + idx]      = acc;
        logd_out[(size_t)n0 * V + idx] = log_d[(size_t)n0 * V + idx];
    }
}

// ---- ridge penalty scalars over params [NCOEF, L] ----
__global__ __launch_bounds__(256) void decor_scalars(
    const float* __restrict__ params, float* __restrict__ outs)
{
    int tid = threadIdx.x;
    float s_par = 0.f, s_fir = 0.f, s_sec = 0.f;
    for (int idx = tid; idx < NCOEF * L; idx += 256) {
        int k = idx / L;
        float p0 = params[idx];
        s_par += p0 * p0;
        if (k + 1 < NCOEF) {
            float p1 = params[idx + L];
            float d1 = p1 - p0;
            s_fir += d1 * d1;
            if (k + 2 < NCOEF) {
                float p2 = params[idx + 2 * L];
                float d2 = p2 - 2.f * p1 + p0;
                s_sec += d2 * d2;
            }
        }
    }
    // wave reduce (64 lanes)
    for (int off = 32; off > 0; off >>= 1) {
        s_par += __shfl_down(s_par, off);
        s_fir += __shfl_down(s_fir, off);
        s_sec += __shfl_down(s_sec, off);
    }
    __shared__ float red[3][4];
    int wave = tid >> 6, lane = tid & 63;
    if (lane == 0) { red[0][wave] = s_sec; red[1][wave] = s_fir; red[2][wave] = s_par; }
    __syncthreads();
    if (tid == 0) {
        float t0 = 0.f, t1 = 0.f, t2 = 0.f;
        for (int w = 0; w < 4; ++w) { t0 += red[0][w]; t1 += red[1][w]; t2 += red[2][w]; }
        outs[0] = t0;  // sec
        outs[1] = t1;  // fir
        outs[2] = t2;  // par
    }
}

extern "C" void kernel_launch(void* const* d_in, const int* in_sizes, int n_in,
                              void* d_out, int out_size, void* d_ws, size_t ws_size,
                              hipStream_t stream) {
    const float* x      = (const float*)d_in[0];
    const float* log_d  = (const float*)d_in[1];
    const float* params = (const float*)d_in[2];

    float* out      = (float*)d_out;                       // [N, V]
    float* M        = out + (size_t)NSAMP * V;             // [N, V, V]
    float* logd_out = M + (size_t)NSAMP * V * V;           // [N, V]
    float* scal     = logd_out + (size_t)NSAMP * V;        // sec, fir, par

    decor_main<<<NSAMP / 64, 256, 0, stream>>>(x, log_d, params, out, M, logd_out);
    decor_scalars<<<1, 256, 0, stream>>>(params, scal);
}

// Round 2
// 26.148 us; speedup vs baseline: 1.0612x; 1.0612x over previous
//
#include <hip/hip_runtime.h>

#define V 10
#define L 45            // V*(V-1)/2
#define NCOEF 14
#define NSAMP 65536
#define BS 64           // samples per block

__global__ __launch_bounds__(256) void decor_fused(
    const float* __restrict__ x, const float* __restrict__ log_d,
    const float* __restrict__ params,
    float* __restrict__ out, float* __restrict__ Mout, float* __restrict__ logd_out,
    float* __restrict__ scal)
{
    __shared__ float xs[BS * V];        // 2.56 KB
    __shared__ float Ms[BS * V * V];    // 25.6 KB
    __shared__ float os[BS * V];        // 2.56 KB

    const int tid = threadIdx.x;
    const int n0  = blockIdx.x * BS;

    // ---- x tile load (float4, 160 loads) ----
    const float4* x4 = (const float4*)(x + (size_t)n0 * V);
    for (int idx = tid; idx < BS * V / 4; idx += 256)
        ((float4*)xs)[idx] = x4[idx];

    // ---- log_d passthrough: straight float4 global->global copy ----
    const float4* ld4  = (const float4*)(log_d + (size_t)n0 * V);
    float4*       ldo4 = (float4*)(logd_out + (size_t)n0 * V);
    for (int idx = tid; idx < BS * V / 4; idx += 256)
        ldo4[idx] = ld4[idx];

    __syncthreads();

    // ---- build M in LDS: diag=1, upper=0, lower=cubic-B-spline lambda ----
    // uniform knots, spacing d = 10/11; u = (x+5)/d + 3
    const float inv_d = 1.1f;
    const float c16   = 1.0f / 6.0f;
    for (int idx = tid; idx < BS * V * V; idx += 256) {
        int nl = idx / (V * V);
        int ij = idx - nl * (V * V);
        int i = ij / V, j = ij - i * V;
        float v;
        if (j > i)       v = 0.0f;
        else if (j == i) v = 1.0f;
        else {
            float xv = xs[nl * V + j];
            xv = fminf(fmaxf(xv, -5.0f), 5.0f);
            float u  = (xv + 5.0f) * inv_d + 3.0f;
            int   ii = (int)floorf(u);
            ii = max(3, min(ii, 14));          // ref indicator: x=+5 lands in [t14,t15)
            float f  = u - (float)ii;
            float omf = 1.0f - f;
            float f2 = f * f, f3 = f2 * f;
            float N0 = omf * omf * omf * c16;
            float N1 = (3.0f * f3 - 6.0f * f2 + 4.0f) * c16;
            float N2 = (-3.0f * f3 + 3.0f * f2 + 3.0f * f + 1.0f) * c16;
            float N3 = f3 * c16;               // == 0 when ii==14
            int l  = i * (i - 1) / 2 + j;
            int k0 = ii - 3;
            int k3 = min(k0 + 3, NCOEF - 1);   // B_14 dropped by ref; N3==0 there
            v = N0 * params[(k0    ) * L + l]
              + N1 * params[(k0 + 1) * L + l]
              + N2 * params[(k0 + 2) * L + l]
              + N3 * params[(k3    ) * L + l];
        }
        Ms[idx] = v;
    }
    __syncthreads();

    // ---- out = M @ x (strict-lower + identity) into LDS ----
    for (int idx = tid; idx < BS * V; idx += 256) {
        int nl = idx / V;
        int i  = idx - nl * V;
        float acc = xs[idx];                    // identity diag * x_i
        const float* Mr = &Ms[nl * V * V + i * V];
        for (int j = 0; j < i; ++j)
            acc += Mr[j] * xs[nl * V + j];
        os[idx] = acc;
    }
    __syncthreads();

    // ---- vector stores: M (1600 float4/block), out (160 float4/block) ----
    float4* M4 = (float4*)(Mout + (size_t)n0 * V * V);
    for (int idx = tid; idx < BS * V * V / 4; idx += 256)
        M4[idx] = ((const float4*)Ms)[idx];
    float4* o4 = (float4*)(out + (size_t)n0 * V);
    for (int idx = tid; idx < BS * V / 4; idx += 256)
        o4[idx] = ((const float4*)os)[idx];

    // ---- ridge scalars: one wave of block 0 (params is 630 floats, L2-hot) ----
    if (blockIdx.x == 0 && tid < 64) {
        float s_par = 0.f, s_fir = 0.f, s_sec = 0.f;
        for (int idx = tid; idx < NCOEF * L; idx += 64) {
            int k = idx / L;
            float p0 = params[idx];
            s_par += p0 * p0;
            if (k + 1 < NCOEF) {
                float p1 = params[idx + L];
                float d1 = p1 - p0;
                s_fir += d1 * d1;
                if (k + 2 < NCOEF) {
                    float p2 = params[idx + 2 * L];
                    float d2 = p2 - 2.f * p1 + p0;
                    s_sec += d2 * d2;
                }
            }
        }
        for (int off = 32; off; off >>= 1) {
            s_sec += __shfl_down(s_sec, off);
            s_fir += __shfl_down(s_fir, off);
            s_par += __shfl_down(s_par, off);
        }
        if (tid == 0) { scal[0] = s_sec; scal[1] = s_fir; scal[2] = s_par; }
    }
}

extern "C" void kernel_launch(void* const* d_in, const int* in_sizes, int n_in,
                              void* d_out, int out_size, void* d_ws, size_t ws_size,
                              hipStream_t stream) {
    const float* x      = (const float*)d_in[0];
    const float* log_d  = (const float*)d_in[1];
    const float* params = (const float*)d_in[2];

    float* out      = (float*)d_out;                       // [N, V]
    float* M        = out + (size_t)NSAMP * V;             // [N, V, V]
    float* logd_out = M + (size_t)NSAMP * V * V;           // [N, V]
    float* scal     = logd_out + (size_t)NSAMP * V;        // sec, fir, par

    decor_fused<<<NSAMP / BS, 256, 0, stream>>>(x, log_d, params, out, M, logd_out, scal);
}

// Round 3
// 19.692 us; speedup vs baseline: 1.4092x; 1.3279x over previous
//
#include <hip/hip_runtime.h>

#define V 10
#define L 45            // V*(V-1)/2
#define NCOEF 14
#define NSAMP 65536
#define BS 64           // samples per block
#define LAMP 48         // padded lam row stride

// col index j for pair l (tril_indices(V, k=-1) row-major order)
__constant__ unsigned char c_col[L] = {
    0,
    0,1,
    0,1,2,
    0,1,2,3,
    0,1,2,3,4,
    0,1,2,3,4,5,
    0,1,2,3,4,5,6,
    0,1,2,3,4,5,6,7,
    0,1,2,3,4,5,6,7,8
};

__global__ __launch_bounds__(256) void decor_fused(
    const float* __restrict__ x, const float* __restrict__ log_d,
    const float* __restrict__ params,
    float* __restrict__ out, float* __restrict__ Mout, float* __restrict__ logd_out,
    float* __restrict__ scal)
{
    __shared__ float ps[NCOEF * L];      // 2.52 KB  params staged in LDS
    __shared__ float xs[BS * V];         // 2.56 KB
    __shared__ float lam[BS * LAMP];     // 12.3 KB
    __shared__ float os[BS * V];         // 2.56 KB

    const int tid = threadIdx.x;
    const int n0  = blockIdx.x * BS;

    // ---- params -> LDS (coalesced, 630 floats) ----
    for (int idx = tid; idx < NCOEF * L; idx += 256)
        ps[idx] = params[idx];

    // ---- x tile load (float4) ----
    const float4* x4 = (const float4*)(x + (size_t)n0 * V);
    for (int idx = tid; idx < BS * V / 4; idx += 256)
        ((float4*)xs)[idx] = x4[idx];

    // ---- log_d passthrough (float4 global->global) ----
    const float4* ld4  = (const float4*)(log_d + (size_t)n0 * V);
    float4*       ldo4 = (float4*)(logd_out + (size_t)n0 * V);
    for (int idx = tid; idx < BS * V / 4; idx += 256)
        ldo4[idx] = ld4[idx];

    __syncthreads();

    // ---- lambdas: BS*L = 2880 evals, params gathered from LDS ----
    // uniform knots, spacing d = 10/11; u = (x+5)/d + 3
    const float inv_d = 1.1f;
    const float c16   = 1.0f / 6.0f;
    for (int idx = tid; idx < BS * L; idx += 256) {
        int nl = idx / L;
        int l  = idx - nl * L;
        float xv = xs[nl * V + c_col[l]];
        xv = fminf(fmaxf(xv, -5.0f), 5.0f);
        float u  = (xv + 5.0f) * inv_d + 3.0f;
        int   ii = (int)floorf(u);
        ii = max(3, min(ii, 14));          // ref indicator: x=+5 lands in [t14,t15)
        float f  = u - (float)ii;
        float omf = 1.0f - f;
        float f2 = f * f, f3 = f2 * f;
        float N0 = omf * omf * omf * c16;
        float N1 = (3.0f * f3 - 6.0f * f2 + 4.0f) * c16;
        float N2 = (-3.0f * f3 + 3.0f * f2 + 3.0f * f + 1.0f) * c16;
        float N3 = f3 * c16;               // == 0 when ii==14
        int k0 = ii - 3;
        int k3 = min(k0 + 3, NCOEF - 1);   // B_14 dropped by ref; N3==0 there
        lam[nl * LAMP + l] =
              N0 * ps[(k0    ) * L + l]
            + N1 * ps[(k0 + 1) * L + l]
            + N2 * ps[(k0 + 2) * L + l]
            + N3 * ps[(k3    ) * L + l];
    }
    __syncthreads();

    // ---- assemble + store M as float4 directly from lam (no Ms round-trip) ----
    float4* M4 = (float4*)(Mout + (size_t)n0 * V * V);
    for (int idx = tid; idx < BS * 25; idx += 256) {
        int nl = idx / 25;
        int q  = idx - nl * 25;
        int e  = q * 4;
        const float* lr = &lam[nl * LAMP];
        float4 v;
        float* vp = &v.x;
        #pragma unroll
        for (int t = 0; t < 4; ++t) {
            int ee = e + t;
            int i  = (ee * 205) >> 11;     // ee/10 for ee<100
            int j  = ee - 10 * i;
            float val;
            if (j > i)       val = 0.0f;
            else if (j == i) val = 1.0f;
            else             val = lr[(i * (i - 1)) / 2 + j];
            vp[t] = val;
        }
        M4[idx] = v;
    }

    // ---- out = M @ x (strict-lower + identity) ----
    for (int idx = tid; idx < BS * V; idx += 256) {
        int nl = idx / V;
        int i  = idx - nl * V;
        float acc = xs[idx];
        const float* lr = &lam[nl * LAMP + (i * (i - 1)) / 2];
        for (int j = 0; j < i; ++j)
            acc += lr[j] * xs[nl * V + j];
        os[idx] = acc;
    }
    __syncthreads();

    float4* o4 = (float4*)(out + (size_t)n0 * V);
    for (int idx = tid; idx < BS * V / 4; idx += 256)
        o4[idx] = ((const float4*)os)[idx];

    // ---- ridge scalars: one wave of block 0, params from LDS ----
    if (blockIdx.x == 0 && tid < 64) {
        float s_par = 0.f, s_fir = 0.f, s_sec = 0.f;
        for (int idx = tid; idx < NCOEF * L; idx += 64) {
            int k = idx / L;
            float p0 = ps[idx];
            s_par += p0 * p0;
            if (k + 1 < NCOEF) {
                float p1 = ps[idx + L];
                float d1 = p1 - p0;
                s_fir += d1 * d1;
                if (k + 2 < NCOEF) {
                    float p2 = ps[idx + 2 * L];
                    float d2 = p2 - 2.f * p1 + p0;
                    s_sec += d2 * d2;
                }
            }
        }
        for (int off = 32; off; off >>= 1) {
            s_sec += __shfl_down(s_sec, off);
            s_fir += __shfl_down(s_fir, off);
            s_par += __shfl_down(s_par, off);
        }
        if (tid == 0) { scal[0] = s_sec; scal[1] = s_fir; scal[2] = s_par; }
    }
}

extern "C" void kernel_launch(void* const* d_in, const int* in_sizes, int n_in,
                              void* d_out, int out_size, void* d_ws, size_t ws_size,
                              hipStream_t stream) {
    const float* x      = (const float*)d_in[0];
    const float* log_d  = (const float*)d_in[1];
    const float* params = (const float*)d_in[2];

    float* out      = (float*)d_out;                       // [N, V]
    float* M        = out + (size_t)NSAMP * V;             // [N, V, V]
    float* logd_out = M + (size_t)NSAMP * V * V;           // [N, V]
    float* scal     = logd_out + (size_t)NSAMP * V;        // sec, fir, par

    decor_fused<<<NSAMP / BS, 256, 0, stream>>>(x, log_d, params, out, M, logd_out, scal);
}

// Round 4
// 17.749 us; speedup vs baseline: 1.5634x; 1.1095x over previous
//
#include <hip/hip_runtime.h>

#define V 10
#define L 45            // V*(V-1)/2
#define NCOEF 14
#define NSAMP 65536
#define BS 32           // samples per block
#define LAMP 48         // padded lam row stride

typedef float v4f __attribute__((ext_vector_type(4)));

// col index j for pair l (tril_indices(V, k=-1) row-major order)
__constant__ unsigned char c_col[L] = {
    0,
    0,1,
    0,1,2,
    0,1,2,3,
    0,1,2,3,4,
    0,1,2,3,4,5,
    0,1,2,3,4,5,6,
    0,1,2,3,4,5,6,7,
    0,1,2,3,4,5,6,7,8
};

__global__ __launch_bounds__(256) void decor_fused(
    const float* __restrict__ x, const float* __restrict__ log_d,
    const float* __restrict__ params,
    float* __restrict__ out, float* __restrict__ Mout, float* __restrict__ logd_out,
    float* __restrict__ scal)
{
    __shared__ float ps[NCOEF * L];      // 2.52 KB  params staged in LDS
    __shared__ int   cols[L];            // 180 B
    __shared__ float xs[BS * V];         // 1.28 KB
    __shared__ float lam[BS * LAMP];     // 6.14 KB
    __shared__ float os[BS * V];         // 1.28 KB

    const int tid = threadIdx.x;
    const int n0  = blockIdx.x * BS;

    // ---- params + col table -> LDS (coalesced) ----
    for (int idx = tid; idx < NCOEF * L; idx += 256)
        ps[idx] = params[idx];
    if (tid < L) cols[tid] = c_col[tid];

    // ---- x tile load (float4, nontemporal) ----
    const v4f* x4 = (const v4f*)(x + (size_t)n0 * V);
    for (int idx = tid; idx < BS * V / 4; idx += 256)
        ((v4f*)xs)[idx] = __builtin_nontemporal_load(&x4[idx]);

    // ---- log_d passthrough (nt load -> nt store) ----
    const v4f* ld4  = (const v4f*)(log_d + (size_t)n0 * V);
    v4f*       ldo4 = (v4f*)(logd_out + (size_t)n0 * V);
    for (int idx = tid; idx < BS * V / 4; idx += 256)
        __builtin_nontemporal_store(__builtin_nontemporal_load(&ld4[idx]), &ldo4[idx]);

    __syncthreads();

    // ---- lambdas: BS*L = 1440 evals, params gathered from LDS ----
    // uniform knots, spacing d = 10/11; u = (x+5)/d + 3
    const float inv_d = 1.1f;
    const float c16   = 1.0f / 6.0f;
    for (int idx = tid; idx < BS * L; idx += 256) {
        int nl = idx / L;
        int l  = idx - nl * L;
        float xv = xs[nl * V + cols[l]];
        xv = fminf(fmaxf(xv, -5.0f), 5.0f);
        float u  = (xv + 5.0f) * inv_d + 3.0f;
        int   ii = (int)floorf(u);
        ii = max(3, min(ii, 14));          // ref indicator: x=+5 lands in [t14,t15)
        float f  = u - (float)ii;
        float omf = 1.0f - f;
        float f2 = f * f, f3 = f2 * f;
        float N0 = omf * omf * omf * c16;
        float N1 = (3.0f * f3 - 6.0f * f2 + 4.0f) * c16;
        float N2 = (-3.0f * f3 + 3.0f * f2 + 3.0f * f + 1.0f) * c16;
        float N3 = f3 * c16;               // == 0 when ii==14
        int k0 = ii - 3;
        int k3 = min(k0 + 3, NCOEF - 1);   // B_14 dropped by ref; N3==0 there
        lam[nl * LAMP + l] =
              N0 * ps[(k0    ) * L + l]
            + N1 * ps[(k0 + 1) * L + l]
            + N2 * ps[(k0 + 2) * L + l]
            + N3 * ps[(k3    ) * L + l];
    }
    __syncthreads();

    // ---- assemble + store M as float4 (nontemporal) directly from lam ----
    v4f* M4 = (v4f*)(Mout + (size_t)n0 * V * V);
    for (int idx = tid; idx < BS * 25; idx += 256) {
        int nl = idx / 25;
        int q  = idx - nl * 25;
        int e  = q * 4;
        const float* lr = &lam[nl * LAMP];
        v4f v;
        #pragma unroll
        for (int t = 0; t < 4; ++t) {
            int ee = e + t;
            int i  = (ee * 205) >> 11;     // ee/10 for ee<100
            int j  = ee - 10 * i;
            float val;
            if (j > i)       val = 0.0f;
            else if (j == i) val = 1.0f;
            else             val = lr[(i * (i - 1)) / 2 + j];
            v[t] = val;
        }
        __builtin_nontemporal_store(v, &M4[idx]);
    }

    // ---- out = M @ x (strict-lower + identity) ----
    for (int idx = tid; idx < BS * V; idx += 256) {
        int nl = idx / V;
        int i  = idx - nl * V;
        float acc = xs[idx];
        const float* lr = &lam[nl * LAMP + (i * (i - 1)) / 2];
        for (int j = 0; j < i; ++j)
            acc += lr[j] * xs[nl * V + j];
        os[idx] = acc;
    }
    __syncthreads();

    v4f* o4 = (v4f*)(out + (size_t)n0 * V);
    for (int idx = tid; idx < BS * V / 4; idx += 256)
        __builtin_nontemporal_store(((const v4f*)os)[idx], &o4[idx]);

    // ---- ridge scalars: one wave of block 0, params from LDS ----
    if (blockIdx.x == 0 && tid < 64) {
        float s_par = 0.f, s_fir = 0.f, s_sec = 0.f;
        for (int idx = tid; idx < NCOEF * L; idx += 64) {
            int k = idx / L;
            float p0 = ps[idx];
            s_par += p0 * p0;
            if (k + 1 < NCOEF) {
                float p1 = ps[idx + L];
                float d1 = p1 - p0;
                s_fir += d1 * d1;
                if (k + 2 < NCOEF) {
                    float p2 = ps[idx + 2 * L];
                    float d2 = p2 - 2.f * p1 + p0;
                    s_sec += d2 * d2;
                }
            }
        }
        for (int off = 32; off; off >>= 1) {
            s_sec += __shfl_down(s_sec, off);
            s_fir += __shfl_down(s_fir, off);
            s_par += __shfl_down(s_par, off);
        }
        if (tid == 0) { scal[0] = s_sec; scal[1] = s_fir; scal[2] = s_par; }
    }
}

extern "C" void kernel_launch(void* const* d_in, const int* in_sizes, int n_in,
                              void* d_out, int out_size, void* d_ws, size_t ws_size,
                              hipStream_t stream) {
    const float* x      = (const float*)d_in[0];
    const float* log_d  = (const float*)d_in[1];
    const float* params = (const float*)d_in[2];

    float* out      = (float*)d_out;                       // [N, V]
    float* M        = out + (size_t)NSAMP * V;             // [N, V, V]
    float* logd_out = M + (size_t)NSAMP * V * V;           // [N, V]
    float* scal     = logd_out + (size_t)NSAMP * V;        // sec, fir, par

    decor_fused<<<NSAMP / BS, 256, 0, stream>>>(x, log_d, params, out, M, logd_out, scal);
}